// Round 7
// baseline (223.183 us; speedup 1.0000x reference)
//
#include <hip/hip_runtime.h>
#include <hip/hip_bf16.h>

#define Bb 4
#define Ss 512
#define Hh 768
#define Dd 24
#define Mm 96
#define Oo 768

typedef __bf16 bf16x8 __attribute__((ext_vector_type(8)));
typedef float f32x4 __attribute__((ext_vector_type(4)));

// ---------------------------------------------------------------------------
// Kernel A: Zj = H_j @ Wpj (packed [row][24]), Zi = H_i @ Wpi (padded [row][32],
// slot 24 = 1.0 bias column, 25..31 = 0 -> MFMA-ready B operand rows)
// ---------------------------------------------------------------------------
__global__ __launch_bounds__(256) void proj_kernel(
    const float* __restrict__ Hj, const float* __restrict__ Hi,
    const float* __restrict__ Wpj, const float* __restrict__ Wpi,
    float* __restrict__ Zj, float* __restrict__ Zip)
{
    const int row = blockIdx.x;
    const int which = blockIdx.y;
    const float* src = (which ? Hi : Hj) + (size_t)row * Hh;
    const float* W = which ? Wpi : Wpj;
    __shared__ float rowbuf[Hh];
    __shared__ float partial[8][Dd];
    const int tid = threadIdx.x;
    for (int i = tid; i < Hh; i += 256) rowbuf[i] = src[i];
    __syncthreads();
    if (tid < 192) {
        const int d = tid % Dd;
        const int c = tid / Dd;
        const int h0 = c * 96;
        float s = 0.f;
        #pragma unroll 4
        for (int h = h0; h < h0 + 96; ++h) s = fmaf(rowbuf[h], W[h * Dd + d], s);
        partial[c][d] = s;
    }
    __syncthreads();
    if (tid < Dd) {
        float s = 0.f;
        #pragma unroll
        for (int c = 0; c < 8; ++c) s += partial[c][tid];
        if (which) Zip[(size_t)row * 32 + tid] = s;
        else       Zj[(size_t)row * Dd + tid] = s;
    }
    if (which && tid >= Dd && tid < 32)
        Zip[(size_t)row * 32 + tid] = (tid == 24) ? 1.0f : 0.0f;
}

// ---------------------------------------------------------------------------
// WsT[m][x] = Ws1[x][m]  (96x96 fp32 transpose; x: 0:24=W1j 24:48=W1i
// 48:72=W1h 72:96=W1d). Single block.
// ---------------------------------------------------------------------------
__global__ __launch_bounds__(256) void wst_kernel(
    const float* __restrict__ Ws1, float* __restrict__ WsT)
{
    __shared__ float W[96][97];
    for (int i = threadIdx.x; i < 96 * 96; i += 256) W[i / 96][i % 96] = Ws1[i];
    __syncthreads();
    for (int i = threadIdx.x; i < 96 * 96; i += 256) WsT[i] = W[i % 96][i / 96];
}

// ---------------------------------------------------------------------------
// tj_all[p][m] = bs1[m] + sum_d Zj[p,d] * W1j[d][m]   (coalesced over m)
// ---------------------------------------------------------------------------
__global__ __launch_bounds__(256) void tj_kernel(
    const float* __restrict__ Zj, const float* __restrict__ Ws1,
    const float* __restrict__ bs1, float* __restrict__ tj_all)
{
    const int idx = blockIdx.x * 256 + threadIdx.x;   // 2048*96
    const int p = idx / 96, m = idx % 96;
    float s = bs1[m];
    const float* zr = Zj + (size_t)p * Dd;
    #pragma unroll
    for (int d = 0; d < Dd; ++d) s = fmaf(zr[d], Ws1[d * Mm + m], s);
    tj_all[idx] = s;
}

// ---------------------------------------------------------------------------
// Transpose + fp32->bf16:  dst[c][r] = bf16(src[r][c]),  tiles 32x32
// ---------------------------------------------------------------------------
__global__ __launch_bounds__(256) void transpose_bf16_kernel(
    const float* __restrict__ src, __bf16* __restrict__ dst,
    int R, int C, long sbatch, long dbatch)
{
    const float* s = src + (size_t)blockIdx.z * sbatch;
    __bf16* d = dst + (size_t)blockIdx.z * dbatch;
    __shared__ float t[32][33];
    const int x = threadIdx.x & 31, y = threadIdx.x >> 5;
    const int c0 = blockIdx.x * 32, r0 = blockIdx.y * 32;
    #pragma unroll
    for (int i = 0; i < 4; ++i)
        t[y + 8 * i][x] = s[(size_t)(r0 + y + 8 * i) * C + c0 + x];
    __syncthreads();
    #pragma unroll
    for (int i = 0; i < 4; ++i)
        d[(size_t)(c0 + y + 8 * i) * R + r0 + x] = (__bf16)t[x][y + 8 * i];
}

// ---------------------------------------------------------------------------
// Kernel B (MFMA, v3): per (b,p) block: logits over 512 q + softmax -> bf16.
// K=96 in 3 chunks with STATIC (p-independent) A-operand weights:
//   chunk0: B = Zi[q,k] (+unit slot24)        A = W1i (+ tj[p]+bs1 bias row)
//   chunk1: B = Zj[p,k]*Zi[q,k]               A = W1h
//   chunk2: B = |Zj[p,k]-Zi[q,k]|             A = W1d
// (expansion of Zi@(Zj*W1h + W1i); only bias element is p-dependent)
// Branch-free t-loop; in-lane m-reduction + 2 shfl.
// ---------------------------------------------------------------------------
__global__ __launch_bounds__(256) void pair_kernel(
    const float* __restrict__ Zj, const float* __restrict__ Zip,
    const float* __restrict__ WsT, const float* __restrict__ tj_all,
    const float* __restrict__ ws2, const float* __restrict__ bs2p,
    const int* __restrict__ mask, __bf16* __restrict__ probs)
{
    const int bp = blockIdx.x;
    const int b  = bp >> 9;              // S = 512
    const int tid  = threadIdx.x;
    const int lane = tid & 63;
    const int wid  = tid >> 6;
    const int col  = lane & 15;          // A: m-row / B: q-col
    const int g    = lane >> 4;          // k-quad

    __shared__ float logitsl[Ss];
    __shared__ float red[8];

    float zj8[8];
    if (g < 3) {
        const float* zr = Zj + (size_t)bp * Dd + g * 8;
        const float4 u = *(const float4*)zr;
        const float4 v = *(const float4*)(zr + 4);
        zj8[0]=u.x; zj8[1]=u.y; zj8[2]=u.z; zj8[3]=u.w;
        zj8[4]=v.x; zj8[5]=v.y; zj8[6]=v.z; zj8[7]=v.w;
    } else {
        #pragma unroll
        for (int j = 0; j < 8; ++j) zj8[j] = 0.f;
    }

    // Static A-fragments (same addresses for every block -> L1-hot).
    bf16x8 aw0[6], aw1[6], aw2[6];
    float ws2r[6][4];
    #pragma unroll
    for (int n = 0; n < 6; ++n) {
        const int m = n * 16 + col;
        const float4 w4 = *(const float4*)&ws2[n * 16 + g * 4];
        ws2r[n][0] = w4.x; ws2r[n][1] = w4.y; ws2r[n][2] = w4.z; ws2r[n][3] = w4.w;
        bf16x8 a0, a1, a2;
        if (g < 3) {
            const float* wr = WsT + (size_t)m * 96;
            const float4 i0 = *(const float4*)(wr + 24 + g * 8);
            const float4 i1 = *(const float4*)(wr + 28 + g * 8);
            const float4 h0 = *(const float4*)(wr + 48 + g * 8);
            const float4 h1 = *(const float4*)(wr + 52 + g * 8);
            const float4 d0 = *(const float4*)(wr + 72 + g * 8);
            const float4 d1 = *(const float4*)(wr + 76 + g * 8);
            a0[0]=(__bf16)i0.x; a0[1]=(__bf16)i0.y; a0[2]=(__bf16)i0.z; a0[3]=(__bf16)i0.w;
            a0[4]=(__bf16)i1.x; a0[5]=(__bf16)i1.y; a0[6]=(__bf16)i1.z; a0[7]=(__bf16)i1.w;
            a1[0]=(__bf16)h0.x; a1[1]=(__bf16)h0.y; a1[2]=(__bf16)h0.z; a1[3]=(__bf16)h0.w;
            a1[4]=(__bf16)h1.x; a1[5]=(__bf16)h1.y; a1[6]=(__bf16)h1.z; a1[7]=(__bf16)h1.w;
            a2[0]=(__bf16)d0.x; a2[1]=(__bf16)d0.y; a2[2]=(__bf16)d0.z; a2[3]=(__bf16)d0.w;
            a2[4]=(__bf16)d1.x; a2[5]=(__bf16)d1.y; a2[6]=(__bf16)d1.z; a2[7]=(__bf16)d1.w;
        } else {
            #pragma unroll
            for (int j = 0; j < 8; ++j) { a0[j]=(__bf16)0.f; a1[j]=(__bf16)0.f; a2[j]=(__bf16)0.f; }
            a0[0] = (__bf16)tj_all[(size_t)bp * 96 + m];   // k=24 bias row
        }
        aw0[n] = a0; aw1[n] = a1; aw2[n] = a2;
    }

    // B source: Zip [row][32]; for g==3 the slots 24..31 = [1,0..0] pair with
    // the bias row (chunk0) and zero weights (chunk1/2) -> branch-free.
    const float* zb = Zip + ((size_t)(b * Ss + wid * 128 + col) * 32) + g * 8;

    float4 cu = *(const float4*)zb;
    float4 cv = *(const float4*)(zb + 4);

    for (int t = 0; t < 8; ++t) {
        const float4 u = cu, v = cv;
        if (t + 1 < 8) {
            const float* zr = zb + (size_t)(t + 1) * 16 * 32;
            cu = *(const float4*)zr; cv = *(const float4*)(zr + 4);
        }
        bf16x8 bz, bq, ba;
        bz[0]=(__bf16)u.x; bz[1]=(__bf16)u.y; bz[2]=(__bf16)u.z; bz[3]=(__bf16)u.w;
        bz[4]=(__bf16)v.x; bz[5]=(__bf16)v.y; bz[6]=(__bf16)v.z; bz[7]=(__bf16)v.w;
        bq[0]=(__bf16)(zj8[0]*u.x); bq[1]=(__bf16)(zj8[1]*u.y);
        bq[2]=(__bf16)(zj8[2]*u.z); bq[3]=(__bf16)(zj8[3]*u.w);
        bq[4]=(__bf16)(zj8[4]*v.x); bq[5]=(__bf16)(zj8[5]*v.y);
        bq[6]=(__bf16)(zj8[6]*v.z); bq[7]=(__bf16)(zj8[7]*v.w);
        ba[0]=(__bf16)fabsf(zj8[0]-u.x); ba[1]=(__bf16)fabsf(zj8[1]-u.y);
        ba[2]=(__bf16)fabsf(zj8[2]-u.z); ba[3]=(__bf16)fabsf(zj8[3]-u.w);
        ba[4]=(__bf16)fabsf(zj8[4]-v.x); ba[5]=(__bf16)fabsf(zj8[5]-v.y);
        ba[6]=(__bf16)fabsf(zj8[6]-v.z); ba[7]=(__bf16)fabsf(zj8[7]-v.w);

        f32x4 acc[6];
        #pragma unroll
        for (int n = 0; n < 6; ++n) acc[n] = (f32x4){0.f, 0.f, 0.f, 0.f};
        #pragma unroll
        for (int n = 0; n < 6; ++n) {
            acc[n] = __builtin_amdgcn_mfma_f32_16x16x32_bf16(aw0[n], bz, acc[n], 0, 0, 0);
            acc[n] = __builtin_amdgcn_mfma_f32_16x16x32_bf16(aw1[n], bq, acc[n], 0, 0, 0);
            acc[n] = __builtin_amdgcn_mfma_f32_16x16x32_bf16(aw2[n], ba, acc[n], 0, 0, 0);
        }

        float lsum = 0.f;
        #pragma unroll
        for (int n = 0; n < 6; ++n)
            #pragma unroll
            for (int r = 0; r < 4; ++r)
                lsum = fmaf(fmaxf(acc[n][r], 0.f), ws2r[n][r], lsum);
        lsum += __shfl_xor(lsum, 16);
        lsum += __shfl_xor(lsum, 32);
        if (lane < 16) logitsl[wid * 128 + t * 16 + lane] = lsum;
    }
    __syncthreads();

    // mask + bias + softmax over 512 q (2 per thread)
    const float bs2v = bs2p[0];
    const int* mrow = mask + (size_t)b * Ss;
    float l0 = logitsl[tid]       + bs2v + (1.0f - (float)mrow[tid])       * (-3.402823466e+38f);
    float l1 = logitsl[tid + 256] + bs2v + (1.0f - (float)mrow[tid + 256]) * (-3.402823466e+38f);
    float vmax = fmaxf(l0, l1);
    #pragma unroll
    for (int off = 32; off > 0; off >>= 1) vmax = fmaxf(vmax, __shfl_xor(vmax, off));
    if (lane == 0) red[wid] = vmax;
    __syncthreads();
    const float mx = fmaxf(fmaxf(red[0], red[1]), fmaxf(red[2], red[3]));
    const float e0 = __expf(l0 - mx);
    const float e1 = __expf(l1 - mx);
    float vs = e0 + e1;
    #pragma unroll
    for (int off = 32; off > 0; off >>= 1) vs += __shfl_xor(vs, off);
    if (lane == 0) red[4 + wid] = vs;
    __syncthreads();
    const float inv = 1.0f / (red[4] + red[5] + red[6] + red[7]);
    __bf16* prow = probs + (size_t)bp * Ss;
    prow[tid] = (__bf16)(e0 * inv);
    prow[tid + 256] = (__bf16)(e1 * inv);
}

// ---------------------------------------------------------------------------
// bf16 MFMA GEMM, 64x64 block tile, BK=64, LDS single-buffer (padded) with
// register prefetch of the next K-slab. 4 waves (2x2), wave tile 32x32.
// MODE 0: ctx = probs@HiT(batch) -> Acat seg0 (ctx), seg1 (bf16 Hj), seg2 (ctx*Hj)
// MODE 1: mhid = relu(Acat@Wv1T + bv1) -> bf16
// MODE 2: out  = alpha*(mhid@Wv2T + bv2) -> fp32
// ---------------------------------------------------------------------------
template<int MODE>
__global__ __launch_bounds__(256) void gemm_kernel(
    const __bf16* __restrict__ A, const __bf16* __restrict__ Bt,
    const float* __restrict__ Hjf, const float* __restrict__ bias,
    const float* __restrict__ alphap,
    __bf16* __restrict__ obf, float* __restrict__ of)
{
    constexpr int K = (MODE == 0) ? 512 : (MODE == 1) ? 2304 : 768;
    constexpr int NIT = K / 64;
    constexpr int LDT = 72;

    __shared__ __bf16 As[64 * LDT];
    __shared__ __bf16 Bs[64 * LDT];

    const int tid = threadIdx.x;
    const int lane = tid & 63;
    const int wid = tid >> 6;
    const int col = lane & 15, g = lane >> 4;
    const int wm = wid >> 1, wn = wid & 1;
    const int r0 = blockIdx.x * 64;
    const int n0 = blockIdx.y * 64;
    const __bf16* Btb = (MODE == 0) ? Bt + (size_t)(r0 >> 9) * (Hh * Ss) : Bt;

    const int srow = tid >> 2;
    const int sc8  = (tid & 3) * 16;
    const __bf16* ag = A   + (size_t)(r0 + srow) * K + sc8;
    const __bf16* bg = Btb + (size_t)(n0 + srow) * K + sc8;
    __bf16* asl = &As[srow * LDT + sc8];
    __bf16* bsl = &Bs[srow * LDT + sc8];

    bf16x8 ra0 = *(const bf16x8*)(ag);
    bf16x8 ra1 = *(const bf16x8*)(ag + 8);
    bf16x8 rb0 = *(const bf16x8*)(bg);
    bf16x8 rb1 = *(const bf16x8*)(bg + 8);

    f32x4 acc[2][2];
    #pragma unroll
    for (int mi = 0; mi < 2; ++mi)
        #pragma unroll
        for (int ni = 0; ni < 2; ++ni) acc[mi][ni] = (f32x4){0.f, 0.f, 0.f, 0.f};

    for (int it = 0; it < NIT; ++it) {
        __syncthreads();
        *(bf16x8*)(asl)     = ra0;
        *(bf16x8*)(asl + 8) = ra1;
        *(bf16x8*)(bsl)     = rb0;
        *(bf16x8*)(bsl + 8) = rb1;
        __syncthreads();
        if (it + 1 < NIT) {
            const int kk = (it + 1) * 64;
            ra0 = *(const bf16x8*)(ag + kk);
            ra1 = *(const bf16x8*)(ag + kk + 8);
            rb0 = *(const bf16x8*)(bg + kk);
            rb1 = *(const bf16x8*)(bg + kk + 8);
        }
        #pragma unroll
        for (int h = 0; h < 2; ++h) {
            bf16x8 a0 = *(const bf16x8*)&As[(wm * 32 + col)      * LDT + h * 32 + g * 8];
            bf16x8 a1 = *(const bf16x8*)&As[(wm * 32 + 16 + col) * LDT + h * 32 + g * 8];
            bf16x8 b0 = *(const bf16x8*)&Bs[(wn * 32 + col)      * LDT + h * 32 + g * 8];
            bf16x8 b1 = *(const bf16x8*)&Bs[(wn * 32 + 16 + col) * LDT + h * 32 + g * 8];
            acc[0][0] = __builtin_amdgcn_mfma_f32_16x16x32_bf16(a0, b0, acc[0][0], 0, 0, 0);
            acc[0][1] = __builtin_amdgcn_mfma_f32_16x16x32_bf16(a0, b1, acc[0][1], 0, 0, 0);
            acc[1][0] = __builtin_amdgcn_mfma_f32_16x16x32_bf16(a1, b0, acc[1][0], 0, 0, 0);
            acc[1][1] = __builtin_amdgcn_mfma_f32_16x16x32_bf16(a1, b1, acc[1][1], 0, 0, 0);
        }
    }

    const float al = (MODE == 2) ? alphap[0] : 0.f;
    #pragma unroll
    for (int mi = 0; mi < 2; ++mi) {
        #pragma unroll
        for (int r = 0; r < 4; ++r) {
            const int row = r0 + wm * 32 + mi * 16 + g * 4 + r;
            #pragma unroll
            for (int ni = 0; ni < 2; ++ni) {
                const int cn = n0 + wn * 32 + ni * 16 + col;
                const float v = acc[mi][ni][r];
                if (MODE == 0) {
                    const float hjv = Hjf[(size_t)row * Hh + cn];
                    obf[(size_t)row * 2304 + cn] = (__bf16)v;
                    obf[(size_t)row * 2304 + 768 + cn] = (__bf16)hjv;
                    obf[(size_t)row * 2304 + 1536 + cn] = (__bf16)(v * hjv);
                } else if (MODE == 1) {
                    obf[(size_t)row * Oo + cn] = (__bf16)fmaxf(v + bias[cn], 0.f);
                } else {
                    of[(size_t)row * Hh + cn] = al * (v + bias[cn]);
                }
            }
        }
    }
}

// ---------------------------------------------------------------------------
extern "C" void kernel_launch(void* const* d_in, const int* in_sizes, int n_in,
                              void* d_out, int out_size, void* d_ws, size_t ws_size,
                              hipStream_t stream)
{
    const float* Hj  = (const float*)d_in[0];
    const float* Hi  = (const float*)d_in[1];
    const float* Wpj = (const float*)d_in[2];
    const float* Wpi = (const float*)d_in[3];
    const float* Ws1 = (const float*)d_in[4];
    const float* bs1 = (const float*)d_in[5];
    const float* ws2 = (const float*)d_in[6];
    const float* bs2 = (const float*)d_in[7];
    const float* Wv1 = (const float*)d_in[8];
    const float* bv1 = (const float*)d_in[9];
    const float* Wv2 = (const float*)d_in[10];
    const float* bv2 = (const float*)d_in[11];
    const float* alpha = (const float*)d_in[12];
    const int* mask  = (const int*)d_in[13];

    float* ws = (float*)d_ws;
    float* Zj     = ws;                                  // 49152
    float* Zip    = Zj + 49152;                          // 65536 (2048x32 padded)
    float* WsT    = Zip + 65536;                         // 9216
    float* tj_all = WsT + 9216;                          // 196608
    float* R0f    = tj_all + 196608;                     // 524288
    float* R1f    = R0f + 524288;                        // 786432
    float* Acat_f = R1f + 786432;                        // 2359296
    float* Wv1T_f = Acat_f + 2359296;                    // 884736
    // total ~19.5 MB

    __bf16* probs_bf = (__bf16*)R0f;                     // [2048][512]
    __bf16* Wv2T     = (__bf16*)R0f;                     // [768][768] (after gemm0)
    __bf16* HiT      = (__bf16*)R1f;                     // [4][768][512]
    __bf16* mhid_bf  = (__bf16*)R1f;                     // [2048][768] (after gemm0)
    __bf16* Acat     = (__bf16*)Acat_f;                  // [2048][2304]
    __bf16* Wv1T     = (__bf16*)Wv1T_f;                  // [768][2304]

    proj_kernel<<<dim3(Bb * Ss, 2), 256, 0, stream>>>(Hj, Hi, Wpj, Wpi, Zj, Zip);
    wst_kernel<<<dim3(1), 256, 0, stream>>>(Ws1, WsT);
    tj_kernel<<<dim3(768), 256, 0, stream>>>(Zj, Ws1, bs1, tj_all);
    transpose_bf16_kernel<<<dim3(Hh / 32, Ss / 32, Bb), 256, 0, stream>>>(
        Hi, HiT, Ss, Hh, (long)Ss * Hh, (long)Hh * Ss);
    transpose_bf16_kernel<<<dim3(Oo / 32, 3 * Hh / 32, 1), 256, 0, stream>>>(
        Wv1, Wv1T, 3 * Hh, Oo, 0, 0);
    pair_kernel<<<dim3(Bb * Ss), 256, 0, stream>>>(
        Zj, Zip, WsT, tj_all, ws2, bs2, mask, probs_bf);
    gemm_kernel<0><<<dim3(2048 / 64, Hh / 64), 256, 0, stream>>>(
        probs_bf, HiT, Hj, nullptr, nullptr, Acat, nullptr);
    transpose_bf16_kernel<<<dim3(Hh / 32, Oo / 32, 1), 256, 0, stream>>>(
        Wv2, Wv2T, Oo, Hh, 0, 0);
    gemm_kernel<1><<<dim3(2048 / 64, Oo / 64), 256, 0, stream>>>(
        Acat, Wv1T, nullptr, bv1, nullptr, mhid_bf, nullptr);
    gemm_kernel<2><<<dim3(2048 / 64, Hh / 64), 256, 0, stream>>>(
        mhid_bf, Wv2T, nullptr, bv2, alpha, nullptr, (float*)d_out);
}

// Round 8
// 180.049 us; speedup vs baseline: 1.2396x; 1.2396x over previous
//
#include <hip/hip_runtime.h>
#include <hip/hip_bf16.h>

#define Bb 4
#define Ss 512
#define Hh 768
#define Dd 24
#define Mm 96
#define Oo 768

typedef __bf16 bf16x8 __attribute__((ext_vector_type(8)));
typedef float f32x4 __attribute__((ext_vector_type(4)));

// ---------------------------------------------------------------------------
// Transpose tile helper: dst[c][r] = bf16(src[r][c]), one 32x32 tile.
// ---------------------------------------------------------------------------
__device__ __forceinline__ void transpose_tile(
    const float* __restrict__ s, __bf16* __restrict__ d,
    int R, int C, int bx, int by, float* smem, int tid)
{
    // smem used as t[32][33]
    const int x = tid & 31, y = tid >> 5;
    const int c0 = bx * 32, r0 = by * 32;
    #pragma unroll
    for (int i = 0; i < 4; ++i)
        smem[(y + 8 * i) * 33 + x] = s[(size_t)(r0 + y + 8 * i) * C + c0 + x];
    __syncthreads();
    #pragma unroll
    for (int i = 0; i < 4; ++i)
        d[(size_t)(c0 + y + 8 * i) * R + r0 + x] = (__bf16)smem[x * 33 + (y + 8 * i)];
}

// ---------------------------------------------------------------------------
// prep_kernel: fuses (a) proj (Zj,Zi), (b) HiT transpose, (c) Wv1T transpose,
// (d) Wv2T transpose, (e) Hj->bf16 into Acat seg1. All independent; one
// launch fills the machine instead of 5 serial small launches.
// blocks: [0,4096) proj | [4096,5632) HiT | [5632,7360) Wv1T |
//         [7360,7936) Wv2T | [7936,8704) hjconv
// ---------------------------------------------------------------------------
__global__ __launch_bounds__(256) void prep_kernel(
    const float* __restrict__ Hj, const float* __restrict__ Hi,
    const float* __restrict__ Wpj, const float* __restrict__ Wpi,
    const float* __restrict__ Wv1, const float* __restrict__ Wv2,
    float* __restrict__ Zj, float* __restrict__ Zi,
    __bf16* __restrict__ HiT, __bf16* __restrict__ Wv1T,
    __bf16* __restrict__ Wv2T, __bf16* __restrict__ Acat)
{
    __shared__ float smem[1088];
    const int bid = blockIdx.x;
    const int tid = threadIdx.x;

    if (bid < 4096) {
        // ---- proj: Zj = H_j @ Wpj, Zi = H_i @ Wpi (both packed [row][24])
        const int row = bid & 2047;
        const int which = bid >> 11;
        const float* src = (which ? Hi : Hj) + (size_t)row * Hh;
        const float* W = which ? Wpi : Wpj;
        float* Z = which ? Zi : Zj;
        float* rowbuf = smem;            // [768]
        float* partial = smem + 768;     // [8][24]
        for (int i = tid; i < Hh; i += 256) rowbuf[i] = src[i];
        __syncthreads();
        if (tid < 192) {
            const int d = tid % Dd;
            const int c = tid / Dd;
            const int h0 = c * 96;
            float s = 0.f;
            #pragma unroll 4
            for (int h = h0; h < h0 + 96; ++h) s = fmaf(rowbuf[h], W[h * Dd + d], s);
            partial[c * Dd + d] = s;
        }
        __syncthreads();
        if (tid < Dd) {
            float s = 0.f;
            #pragma unroll
            for (int c = 0; c < 8; ++c) s += partial[c * Dd + tid];
            Z[(size_t)row * Dd + tid] = s;
        }
    } else if (bid < 5632) {
        // ---- HiT[b][h][q] = bf16(Hi[b][q][h]);  R=Ss, C=Hh, grid 24x16x4
        int rem = bid - 4096;
        const int bz = rem / 384; rem %= 384;
        transpose_tile(Hi + (size_t)bz * Ss * Hh, HiT + (size_t)bz * Hh * Ss,
                       Ss, Hh, rem % 24, rem / 24, smem, tid);
    } else if (bid < 7360) {
        // ---- Wv1T[o][k] = bf16(Wv1[k][o]);  R=2304, C=768, grid 24x72
        const int rem = bid - 5632;
        transpose_tile(Wv1, Wv1T, 3 * Hh, Oo, rem % 24, rem / 24, smem, tid);
    } else if (bid < 7936) {
        // ---- Wv2T[h][o] = bf16(Wv2[o][h]);  R=768, C=768, grid 24x24
        const int rem = bid - 7360;
        transpose_tile(Wv2, Wv2T, Oo, Hh, rem % 24, rem / 24, smem, tid);
    } else {
        // ---- hjconv: Acat seg1 = bf16(Hj)
        const int idx = (bid - 7936) * 256 + tid;   // [0, 2048*96)
        const int row = idx / 96, c8 = idx % 96;
        const float* s = Hj + (size_t)row * Hh + c8 * 8;
        const float4 u = *(const float4*)s;
        const float4 v = *(const float4*)(s + 4);
        bf16x8 o;
        o[0]=(__bf16)u.x; o[1]=(__bf16)u.y; o[2]=(__bf16)u.z; o[3]=(__bf16)u.w;
        o[4]=(__bf16)v.x; o[5]=(__bf16)v.y; o[6]=(__bf16)v.z; o[7]=(__bf16)v.w;
        *(bf16x8*)&Acat[(size_t)row * 2304 + Hh + c8 * 8] = o;
    }
}

// ---------------------------------------------------------------------------
// Kernel B (MFMA): per (b,p) block: logits over all 512 q + softmax -> bf16
// probs. (Exact R4 version — best measured variant.)
// ---------------------------------------------------------------------------
__global__ __launch_bounds__(256) void pair_kernel(
    const float* __restrict__ Zj, const float* __restrict__ Zi,
    const float* __restrict__ Ws1, const float* __restrict__ bs1,
    const float* __restrict__ ws2, const float* __restrict__ bs2p,
    const int* __restrict__ mask, __bf16* __restrict__ probs)
{
    const int bp = blockIdx.x;
    const int b  = bp >> 9;              // S = 512
    const int tid  = threadIdx.x;
    const int lane = tid & 63;
    const int wid  = tid >> 6;
    const int col  = lane & 15;
    const int g    = lane >> 4;

    __shared__ float zjall[Dd];
    __shared__ float rowadd[Mm];
    __shared__ float logitsl[Ss];
    __shared__ float red[8];

    if (tid < Dd) zjall[tid] = Zj[(size_t)bp * Dd + tid];
    __syncthreads();
    if (tid < Mm) {
        float s = bs1[tid];
        #pragma unroll
        for (int d = 0; d < Dd; ++d) s = fmaf(zjall[d], Ws1[d * Mm + tid], s);
        rowadd[tid] = s;
    }
    __syncthreads();

    float zj8[8];
    if (g < 3) {
        const float* zr = Zj + (size_t)bp * Dd + g * 8;
        const float4 u = *(const float4*)zr;
        const float4 v = *(const float4*)(zr + 4);
        zj8[0]=u.x; zj8[1]=u.y; zj8[2]=u.z; zj8[3]=u.w;
        zj8[4]=v.x; zj8[5]=v.y; zj8[6]=v.z; zj8[7]=v.w;
    } else {
        #pragma unroll
        for (int j = 0; j < 8; ++j) zj8[j] = 0.f;
    }

    bf16x8 bw[6][2];
    float ws2r[6];
    #pragma unroll
    for (int n = 0; n < 6; ++n) {
        const int m = n * 16 + col;
        ws2r[n] = ws2[m];
        bf16x8 b0, b1;
        if (g < 3) {
            #pragma unroll
            for (int j = 0; j < 8; ++j) {
                const int d = g * 8 + j;
                b0[j] = (__bf16)(fmaf(zj8[j], Ws1[(2 * Dd + d) * Mm + m],
                                      Ws1[(Dd + d) * Mm + m]));
                b1[j] = (__bf16)(Ws1[(3 * Dd + d) * Mm + m]);
            }
        } else {
            #pragma unroll
            for (int j = 0; j < 8; ++j) { b0[j] = (__bf16)0.f; b1[j] = (__bf16)0.f; }
            b0[0] = (__bf16)rowadd[m];
        }
        bw[n][0] = b0; bw[n][1] = b1;
    }

    const float* zib = Zi + (size_t)b * Ss * Dd;

    #pragma unroll 2
    for (int t = 0; t < 8; ++t) {
        const int q0 = wid * 128 + t * 16;
        bf16x8 a0, a1;
        if (g < 3) {
            const float* zr = zib + (size_t)(q0 + col) * Dd + g * 8;
            const float4 u = *(const float4*)zr;
            const float4 v = *(const float4*)(zr + 4);
            a0[0]=(__bf16)u.x; a0[1]=(__bf16)u.y; a0[2]=(__bf16)u.z; a0[3]=(__bf16)u.w;
            a0[4]=(__bf16)v.x; a0[5]=(__bf16)v.y; a0[6]=(__bf16)v.z; a0[7]=(__bf16)v.w;
            a1[0]=(__bf16)fabsf(zj8[0]-u.x); a1[1]=(__bf16)fabsf(zj8[1]-u.y);
            a1[2]=(__bf16)fabsf(zj8[2]-u.z); a1[3]=(__bf16)fabsf(zj8[3]-u.w);
            a1[4]=(__bf16)fabsf(zj8[4]-v.x); a1[5]=(__bf16)fabsf(zj8[5]-v.y);
            a1[6]=(__bf16)fabsf(zj8[6]-v.z); a1[7]=(__bf16)fabsf(zj8[7]-v.w);
        } else {
            #pragma unroll
            for (int j = 0; j < 8; ++j) { a0[j] = (__bf16)0.f; a1[j] = (__bf16)0.f; }
            a0[0] = (__bf16)1.0f;
        }

        f32x4 acc[6];
        #pragma unroll
        for (int n = 0; n < 6; ++n) acc[n] = (f32x4){0.f, 0.f, 0.f, 0.f};
        #pragma unroll
        for (int n = 0; n < 6; ++n) {
            acc[n] = __builtin_amdgcn_mfma_f32_16x16x32_bf16(a0, bw[n][0], acc[n], 0, 0, 0);
            acc[n] = __builtin_amdgcn_mfma_f32_16x16x32_bf16(a1, bw[n][1], acc[n], 0, 0, 0);
        }

        float lsum[4] = {0.f, 0.f, 0.f, 0.f};
        #pragma unroll
        for (int n = 0; n < 6; ++n)
            #pragma unroll
            for (int r = 0; r < 4; ++r)
                lsum[r] = fmaf(fmaxf(acc[n][r], 0.f), ws2r[n], lsum[r]);
        #pragma unroll
        for (int off = 1; off <= 8; off <<= 1) {
            #pragma unroll
            for (int r = 0; r < 4; ++r) lsum[r] += __shfl_xor(lsum[r], off);
        }
        if (col == 0) {
            float4 o = {lsum[0], lsum[1], lsum[2], lsum[3]};
            *(float4*)&logitsl[q0 + g * 4] = o;
        }
    }
    __syncthreads();

    const float bs2v = bs2p[0];
    const int* mrow = mask + (size_t)b * Ss;
    float l0 = logitsl[tid]       + bs2v + (1.0f - (float)mrow[tid])       * (-3.402823466e+38f);
    float l1 = logitsl[tid + 256] + bs2v + (1.0f - (float)mrow[tid + 256]) * (-3.402823466e+38f);
    float vmax = fmaxf(l0, l1);
    #pragma unroll
    for (int off = 32; off > 0; off >>= 1) vmax = fmaxf(vmax, __shfl_xor(vmax, off));
    if (lane == 0) red[wid] = vmax;
    __syncthreads();
    const float mx = fmaxf(fmaxf(red[0], red[1]), fmaxf(red[2], red[3]));
    const float e0 = __expf(l0 - mx);
    const float e1 = __expf(l1 - mx);
    float vs = e0 + e1;
    #pragma unroll
    for (int off = 32; off > 0; off >>= 1) vs += __shfl_xor(vs, off);
    if (lane == 0) red[4 + wid] = vs;
    __syncthreads();
    const float inv = 1.0f / (red[4] + red[5] + red[6] + red[7]);
    __bf16* prow = probs + (size_t)bp * Ss;
    prow[tid] = (__bf16)(e0 * inv);
    prow[tid + 256] = (__bf16)(e1 * inv);
}

// ---------------------------------------------------------------------------
// bf16 MFMA GEMM (exact R4 version), 64x64 tile, BK=64, LDS single-buffer
// + register prefetch. MODE 0: ctx -> Acat seg0 & seg2 (seg1 done in prep).
// MODE 1: mhid = relu(Acat@Wv1T + bv1). MODE 2: out = alpha*(mhid@Wv2T+bv2).
// ---------------------------------------------------------------------------
template<int MODE>
__global__ __launch_bounds__(256) void gemm_kernel(
    const __bf16* __restrict__ A, const __bf16* __restrict__ Bt,
    const float* __restrict__ Hjf, const float* __restrict__ bias,
    const float* __restrict__ alphap,
    __bf16* __restrict__ obf, float* __restrict__ of)
{
    constexpr int K = (MODE == 0) ? 512 : (MODE == 1) ? 2304 : 768;
    constexpr int NIT = K / 64;
    constexpr int LDT = 72;

    __shared__ __bf16 As[64 * LDT];
    __shared__ __bf16 Bs[64 * LDT];

    const int tid = threadIdx.x;
    const int lane = tid & 63;
    const int wid = tid >> 6;
    const int col = lane & 15, g = lane >> 4;
    const int wm = wid >> 1, wn = wid & 1;
    const int r0 = blockIdx.x * 64;
    const int n0 = blockIdx.y * 64;
    const __bf16* Btb = (MODE == 0) ? Bt + (size_t)(r0 >> 9) * (Hh * Ss) : Bt;

    const int srow = tid >> 2;
    const int sc8  = (tid & 3) * 16;
    const __bf16* ag = A   + (size_t)(r0 + srow) * K + sc8;
    const __bf16* bg = Btb + (size_t)(n0 + srow) * K + sc8;
    __bf16* asl = &As[srow * LDT + sc8];
    __bf16* bsl = &Bs[srow * LDT + sc8];

    bf16x8 ra0 = *(const bf16x8*)(ag);
    bf16x8 ra1 = *(const bf16x8*)(ag + 8);
    bf16x8 rb0 = *(const bf16x8*)(bg);
    bf16x8 rb1 = *(const bf16x8*)(bg + 8);

    f32x4 acc[2][2];
    #pragma unroll
    for (int mi = 0; mi < 2; ++mi)
        #pragma unroll
        for (int ni = 0; ni < 2; ++ni) acc[mi][ni] = (f32x4){0.f, 0.f, 0.f, 0.f};

    for (int it = 0; it < NIT; ++it) {
        __syncthreads();
        *(bf16x8*)(asl)     = ra0;
        *(bf16x8*)(asl + 8) = ra1;
        *(bf16x8*)(bsl)     = rb0;
        *(bf16x8*)(bsl + 8) = rb1;
        __syncthreads();
        if (it + 1 < NIT) {
            const int kk = (it + 1) * 64;
            ra0 = *(const bf16x8*)(ag + kk);
            ra1 = *(const bf16x8*)(ag + kk + 8);
            rb0 = *(const bf16x8*)(bg + kk);
            rb1 = *(const bf16x8*)(bg + kk + 8);
        }
        #pragma unroll
        for (int h = 0; h < 2; ++h) {
            bf16x8 a0 = *(const bf16x8*)&As[(wm * 32 + col)      * LDT + h * 32 + g * 8];
            bf16x8 a1 = *(const bf16x8*)&As[(wm * 32 + 16 + col) * LDT + h * 32 + g * 8];
            bf16x8 b0 = *(const bf16x8*)&Bs[(wn * 32 + col)      * LDT + h * 32 + g * 8];
            bf16x8 b1 = *(const bf16x8*)&Bs[(wn * 32 + 16 + col) * LDT + h * 32 + g * 8];
            acc[0][0] = __builtin_amdgcn_mfma_f32_16x16x32_bf16(a0, b0, acc[0][0], 0, 0, 0);
            acc[0][1] = __builtin_amdgcn_mfma_f32_16x16x32_bf16(a0, b1, acc[0][1], 0, 0, 0);
            acc[1][0] = __builtin_amdgcn_mfma_f32_16x16x32_bf16(a1, b0, acc[1][0], 0, 0, 0);
            acc[1][1] = __builtin_amdgcn_mfma_f32_16x16x32_bf16(a1, b1, acc[1][1], 0, 0, 0);
        }
    }

    const float al = (MODE == 2) ? alphap[0] : 0.f;
    #pragma unroll
    for (int mi = 0; mi < 2; ++mi) {
        #pragma unroll
        for (int r = 0; r < 4; ++r) {
            const int row = r0 + wm * 32 + mi * 16 + g * 4 + r;
            #pragma unroll
            for (int ni = 0; ni < 2; ++ni) {
                const int cn = n0 + wn * 32 + ni * 16 + col;
                const float v = acc[mi][ni][r];
                if (MODE == 0) {
                    const float hjv = Hjf[(size_t)row * Hh + cn];
                    obf[(size_t)row * 2304 + cn] = (__bf16)v;
                    obf[(size_t)row * 2304 + 1536 + cn] = (__bf16)(v * hjv);
                } else if (MODE == 1) {
                    obf[(size_t)row * Oo + cn] = (__bf16)fmaxf(v + bias[cn], 0.f);
                } else {
                    of[(size_t)row * Hh + cn] = al * (v + bias[cn]);
                }
            }
        }
    }
}

// ---------------------------------------------------------------------------
extern "C" void kernel_launch(void* const* d_in, const int* in_sizes, int n_in,
                              void* d_out, int out_size, void* d_ws, size_t ws_size,
                              hipStream_t stream)
{
    const float* Hj  = (const float*)d_in[0];
    const float* Hi  = (const float*)d_in[1];
    const float* Wpj = (const float*)d_in[2];
    const float* Wpi = (const float*)d_in[3];
    const float* Ws1 = (const float*)d_in[4];
    const float* bs1 = (const float*)d_in[5];
    const float* ws2 = (const float*)d_in[6];
    const float* bs2 = (const float*)d_in[7];
    const float* Wv1 = (const float*)d_in[8];
    const float* bv1 = (const float*)d_in[9];
    const float* Wv2 = (const float*)d_in[10];
    const float* bv2 = (const float*)d_in[11];
    const float* alpha = (const float*)d_in[12];
    const int* mask  = (const int*)d_in[13];

    // workspace (float units) — all regions DISTINCT (no lifetime overlays)
    float* ws = (float*)d_ws;
    float* Zj      = ws;                  // 49152
    float* Zi      = Zj + 49152;          // 49152
    float* probs_f = Zi + 49152;          // 524288
    float* HiT_f   = probs_f + 524288;    // 786432
    float* Wv2T_f  = HiT_f + 786432;      // 294912
    float* mhid_f  = Wv2T_f + 294912;     // 786432
    float* Acat_f  = mhid_f + 786432;     // 2359296
    float* Wv1T_f  = Acat_f + 2359296;    // 884736
    // total 5,734,400 floats = 22.9 MB

    __bf16* probs_bf = (__bf16*)probs_f;  // [2048][512]
    __bf16* HiT      = (__bf16*)HiT_f;    // [4][768][512]
    __bf16* Wv2T     = (__bf16*)Wv2T_f;   // [768][768]
    __bf16* mhid_bf  = (__bf16*)mhid_f;   // [2048][768]
    __bf16* Acat     = (__bf16*)Acat_f;   // [2048][2304]
    __bf16* Wv1T     = (__bf16*)Wv1T_f;   // [768][2304]

    prep_kernel<<<dim3(8704), 256, 0, stream>>>(
        Hj, Hi, Wpj, Wpi, Wv1, Wv2, Zj, Zi, HiT, Wv1T, Wv2T, Acat);
    pair_kernel<<<dim3(Bb * Ss), 256, 0, stream>>>(
        Zj, Zi, Ws1, bs1, ws2, bs2, mask, probs_bf);
    gemm_kernel<0><<<dim3(2048 / 64, Hh / 64), 256, 0, stream>>>(
        probs_bf, HiT, Hj, nullptr, nullptr, Acat, nullptr);
    gemm_kernel<1><<<dim3(2048 / 64, Oo / 64), 256, 0, stream>>>(
        Acat, Wv1T, nullptr, bv1, nullptr, mhid_bf, nullptr);
    gemm_kernel<2><<<dim3(2048 / 64, Hh / 64), 256, 0, stream>>>(
        mhid_bf, Wv2T, nullptr, bv2, alpha, nullptr, (float*)d_out);
}